// Round 6
// baseline (284.109 us; speedup 1.0000x reference)
//
#include <hip/hip_runtime.h>

#define B_N 131072
#define IN_N 40
#define H_N 256

typedef __bf16 bf16x8 __attribute__((ext_vector_type(8)));
typedef float f32x4 __attribute__((ext_vector_type(4)));

#define MFMA(a, b, c) __builtin_amdgcn_mfma_f32_16x16x32_bf16(a, b, c, 0, 0, 0)

// ws bf16 layout (transposed weights so a wave's B-frag load is 1KB contiguous):
//   WT_GH [3][8][256][32] : (gate, ks, col, e) <- Whh[(g*256+col)*256 + ks*32 + e]
//   WT_GI [3][2][256][32] : k=ks2*32+e, fused W_ih@W_proj, zero for k>=40
//   bfused f32[768] = b_ih + W_ih@b_proj
#define WSGH 0
#define WSGI 196608
#define WSBI 245760
#define PREP_N (245760 + 768 + B_N)

__global__ void prep(const float* __restrict__ Wp, const float* __restrict__ bp,
                     const float* __restrict__ Wih, const float* __restrict__ Whh,
                     const float* __restrict__ bih, const float* __restrict__ bhead,
                     __bf16* __restrict__ wsb, float* __restrict__ out) {
  int i = blockIdx.x * 256 + threadIdx.x;
  if (i < WSGI) {
    int e = i & 31, col = (i >> 5) & 255, ks = (i >> 13) & 7, g = i >> 16;
    wsb[i] = (__bf16)Whh[(g * 256 + col) * 256 + ks * 32 + e];
  } else if (i < WSBI) {
    int j = i - WSGI;
    int e = j & 31, col = (j >> 5) & 255, ks2 = (j >> 13) & 1, g = j >> 14;
    int k = ks2 * 32 + e;
    float v = 0.f;
    if (k < IN_N) {
      for (int p = 0; p < 128; ++p) v += Wih[(g * 256 + col) * 128 + p] * Wp[p * IN_N + k];
    }
    wsb[i] = (__bf16)v;
  } else if (i < WSBI + 768) {
    int g = i - WSBI;
    float v = bih[g];
    for (int p = 0; p < 128; ++p) v += Wih[g * 128 + p] * bp[p];
    ((float*)(wsb + WSBI))[g] = v;
  } else if (i < PREP_N) {
    out[i - (WSBI + 768)] = bhead[0];  // pred init = bias; blocks atomicAdd partials
  }
}

// 256 thr = 4 waves; block = 64 rows x 64 cols (col quarter), loops 8 row-segs.
// Weights streamed from L2 via 2-deep register window; h double-buffered in LDS
// (XOR-swizzled, T14 split staging); x single-buffered.
__global__ __launch_bounds__(256, 2) void gru_v7(
    const float* __restrict__ x, const float* __restrict__ h0,
    const __bf16* __restrict__ wsb, const float* __restrict__ bhh,
    const float* __restrict__ Whead, float* __restrict__ out) {
  __shared__ __align__(16) __bf16 hs[2][64 * 256];  // swizzled: chunk ^= row&7
  __shared__ __align__(16) __bf16 xs[64][72];       // K padded 40->64, +8 pad

  const int tid = threadIdx.x;
  const int lane = tid & 63;
  const int w = tid >> 6;
  const int l15 = lane & 15;
  const int l4 = lane >> 4;

  // XCD-chunked: each XCD gets contiguous (rowseg, quarter) span -> h L2 reuse
  const int b = blockIdx.x;
  const int lin = (b & 7) * 128 + (b >> 3);
  const int ch = lin & 3;
  const int seg0 = (lin >> 2) * 8;

  const int cb = ch * 64 + w * 16;
  const int col = cb + l15;

  const __bf16* lgh = wsb + WSGH + (size_t)(cb + l15) * 32 + l4 * 8;
  const __bf16* lgi = wsb + WSGI + (size_t)(cb + l15) * 32 + l4 * 8;

  const float* bfused = (const float*)(wsb + WSBI);
  const float bR = bfused[col] + bhh[col];
  const float bZ = bfused[256 + col] + bhh[256 + col];
  const float bI = bfused[512 + col];
  const float bH = bhh[512 + col];
  const float whead = Whead[col];

  // zero-fill xs pad cols 40..63 once (never overwritten)
  for (int j = tid; j < 64 * 24; j += 256) xs[j / 24][40 + j % 24] = (__bf16)0.f;

  float4 svA[4], svB[4], xv[4];

  auto loadH = [&](float4(&sv)[4], int seg, int q) {
#pragma unroll
    for (int kk = 0; kk < 2; ++kk) {
      const int cid = tid + kk * 256;
      const int rl = q * 16 + (cid >> 5), ck = cid & 31;
      const float* src = h0 + ((size_t)seg * 64 + rl) * H_N + ck * 8;
      sv[kk * 2] = *reinterpret_cast<const float4*>(src);
      sv[kk * 2 + 1] = *reinterpret_cast<const float4*>(src + 4);
    }
  };
  auto writeH = [&](float4(&sv)[4], int buf, int q) {
#pragma unroll
    for (int kk = 0; kk < 2; ++kk) {
      const int cid = tid + kk * 256;
      const int rl = q * 16 + (cid >> 5), ck = cid & 31;
      bf16x8 u;
      u[0] = (__bf16)sv[kk * 2].x; u[1] = (__bf16)sv[kk * 2].y;
      u[2] = (__bf16)sv[kk * 2].z; u[3] = (__bf16)sv[kk * 2].w;
      u[4] = (__bf16)sv[kk * 2 + 1].x; u[5] = (__bf16)sv[kk * 2 + 1].y;
      u[6] = (__bf16)sv[kk * 2 + 1].z; u[7] = (__bf16)sv[kk * 2 + 1].w;
      *reinterpret_cast<bf16x8*>(&hs[buf][rl * 256 + ((ck ^ (rl & 7)) << 3)]) = u;
    }
  };
  auto loadX = [&](int seg) {
    const int c0 = tid, c1 = 256 + (tid & 63);
    const float* sx = x + (size_t)seg * 64 * IN_N;
    xv[0] = *reinterpret_cast<const float4*>(sx + c0 * 8);
    xv[1] = *reinterpret_cast<const float4*>(sx + c0 * 8 + 4);
    xv[2] = *reinterpret_cast<const float4*>(sx + c1 * 8);
    xv[3] = *reinterpret_cast<const float4*>(sx + c1 * 8 + 4);
  };
  auto writeX = [&]() {
    const int c0 = tid, c1 = 256 + (tid & 63);
    bf16x8 u0, u1;
    u0[0] = (__bf16)xv[0].x; u0[1] = (__bf16)xv[0].y; u0[2] = (__bf16)xv[0].z; u0[3] = (__bf16)xv[0].w;
    u0[4] = (__bf16)xv[1].x; u0[5] = (__bf16)xv[1].y; u0[6] = (__bf16)xv[1].z; u0[7] = (__bf16)xv[1].w;
    u1[0] = (__bf16)xv[2].x; u1[1] = (__bf16)xv[2].y; u1[2] = (__bf16)xv[2].z; u1[3] = (__bf16)xv[2].w;
    u1[4] = (__bf16)xv[3].x; u1[5] = (__bf16)xv[3].y; u1[6] = (__bf16)xv[3].z; u1[7] = (__bf16)xv[3].w;
    *reinterpret_cast<bf16x8*>(&xs[c0 / 5][(c0 % 5) * 8]) = u0;
    *reinterpret_cast<bf16x8*>(&xs[c1 / 5][(c1 % 5) * 8]) = u1;
  };

  bf16x8 wR[2], wZ[2], wN[2];
  auto loadWgrp = [&](int slot, int grp) {  // grp 0,1 = gi; 2..9 = gh ks 0..7
    if (grp < 2) {
      wR[slot] = *reinterpret_cast<const bf16x8*>(lgi + (0 * 2 + grp) * 8192);
      wZ[slot] = *reinterpret_cast<const bf16x8*>(lgi + (1 * 2 + grp) * 8192);
      wN[slot] = *reinterpret_cast<const bf16x8*>(lgi + (2 * 2 + grp) * 8192);
    } else {
      const int ks = grp - 2;
      wR[slot] = *reinterpret_cast<const bf16x8*>(lgh + (0 * 8 + ks) * 8192);
      wZ[slot] = *reinterpret_cast<const bf16x8*>(lgh + (1 * 8 + ks) * 8192);
      wN[slot] = *reinterpret_cast<const bf16x8*>(lgh + (2 * 8 + ks) * 8192);
    }
  };

  f32x4 aR4[4], aZ4[4], aI4[4], aH4[4];
  auto grpGI = [&](int slot, int ks2) {
#pragma unroll
    for (int mi = 0; mi < 4; ++mi) {
      const bf16x8 a = *reinterpret_cast<const bf16x8*>(&xs[mi * 16 + l15][ks2 * 32 + l4 * 8]);
      aR4[mi] = MFMA(a, wR[slot], aR4[mi]);
      aZ4[mi] = MFMA(a, wZ[slot], aZ4[mi]);
      aI4[mi] = MFMA(a, wN[slot], aI4[mi]);
    }
  };
  auto grpGH = [&](const __bf16* hb, int slot, int ks) {
#pragma unroll
    for (int mi = 0; mi < 4; ++mi) {
      const int row = mi * 16 + l15;
      const int ck = (ks * 4 + l4) ^ (row & 7);
      const bf16x8 a = *reinterpret_cast<const bf16x8*>(&hb[row * 256 + ck * 8]);
      aR4[mi] = MFMA(a, wR[slot], aR4[mi]);
      aZ4[mi] = MFMA(a, wZ[slot], aZ4[mi]);
      aH4[mi] = MFMA(a, wN[slot], aH4[mi]);
    }
  };

  // ---- prologue: stage tile 0, preload window ----
  loadH(svA, seg0, 0); writeH(svA, 0, 0);
  loadH(svA, seg0, 1); writeH(svA, 0, 1);
  loadH(svA, seg0, 2); writeH(svA, 0, 2);
  loadH(svA, seg0, 3); writeH(svA, 0, 3);
  loadX(seg0); writeX();
  loadWgrp(0, 0); loadWgrp(1, 1);
  __syncthreads();

  for (int t = 0; t < 8; ++t) {
    const int cur = t & 1;
    const int seg = seg0 + t;
    const int nseg = (t < 7) ? seg + 1 : seg;  // clamp; redundant reload, never read
    const __bf16* hb = hs[cur];

#pragma unroll
    for (int mi = 0; mi < 4; ++mi) {
      aR4[mi] = (f32x4){bR, bR, bR, bR};
      aZ4[mi] = (f32x4){bZ, bZ, bZ, bZ};
      aI4[mi] = (f32x4){bI, bI, bI, bI};
      aH4[mi] = (f32x4){bH, bH, bH, bH};
    }

    // gi phase (reads xs)
    grpGI(0, 0); loadWgrp(0, 2);
    grpGI(1, 1); loadWgrp(1, 3);
    __syncthreads();  // all waves done with xs(t)

    // gh phase (reads hs[cur]); staging targets hs[cur^1] / xs
    grpGH(hb, 0, 0); loadWgrp(0, 4); loadH(svA, nseg, 0);
    grpGH(hb, 1, 1); loadWgrp(1, 5); loadH(svB, nseg, 1);
    grpGH(hb, 0, 2); loadWgrp(0, 6);
    grpGH(hb, 1, 3); loadWgrp(1, 7); writeH(svA, cur ^ 1, 0); loadH(svA, nseg, 2);
    grpGH(hb, 0, 4); loadWgrp(0, 8); writeH(svB, cur ^ 1, 1); loadH(svB, nseg, 3);
    grpGH(hb, 1, 5); loadWgrp(1, 9); loadX(nseg);
    grpGH(hb, 0, 6); loadWgrp(0, 0); writeH(svA, cur ^ 1, 2);
    grpGH(hb, 1, 7); loadWgrp(1, 1); writeH(svB, cur ^ 1, 3); writeX();

    // epilogue
    float ps[4][4];
#pragma unroll
    for (int mi = 0; mi < 4; ++mi) {
#pragma unroll
      for (int r = 0; r < 4; ++r) {
        const int row = mi * 16 + l4 * 4 + r;
        const float rg = __builtin_amdgcn_rcpf(1.f + __expf(-aR4[mi][r]));
        const float zg = __builtin_amdgcn_rcpf(1.f + __expf(-aZ4[mi][r]));
        const float e2 = __expf(2.f * (aI4[mi][r] + rg * aH4[mi][r]));
        const float ng = 1.f - 2.f * __builtin_amdgcn_rcpf(e2 + 1.f);
        const int ckv = (col >> 3) ^ (row & 7);
        const float hv = (float)hb[row * 256 + ckv * 8 + (col & 7)];
        const float hn = (1.f - zg) * ng + zg * hv;
        out[(size_t)B_N + ((size_t)seg * 64 + row) * H_N + col] = hn;
        ps[mi][r] = hn * whead;
      }
    }
#pragma unroll
    for (int mi = 0; mi < 4; ++mi)
#pragma unroll
      for (int r = 0; r < 4; ++r) {
        float s = ps[mi][r];
        s += __shfl_xor(s, 1);
        s += __shfl_xor(s, 2);
        s += __shfl_xor(s, 4);
        s += __shfl_xor(s, 8);
        ps[mi][r] = s;
      }
    if (l15 == 0) {
#pragma unroll
      for (int mi = 0; mi < 4; ++mi)
#pragma unroll
        for (int r = 0; r < 4; ++r)
          atomicAdd(&out[seg * 64 + mi * 16 + l4 * 4 + r], ps[mi][r]);
    }
    __syncthreads();  // staged hs[cur^1]/xs writes visible to all
  }
}

extern "C" void kernel_launch(void* const* d_in, const int* in_sizes, int n_in,
                              void* d_out, int out_size, void* d_ws, size_t ws_size,
                              hipStream_t stream) {
  const float* x     = (const float*)d_in[0];
  const float* h0    = (const float*)d_in[1];
  const float* Wp    = (const float*)d_in[2];
  const float* bp    = (const float*)d_in[3];
  const float* Wih   = (const float*)d_in[4];
  const float* Whh   = (const float*)d_in[5];
  const float* bih   = (const float*)d_in[6];
  const float* bhh   = (const float*)d_in[7];
  const float* Whead = (const float*)d_in[8];
  const float* bhead = (const float*)d_in[9];
  float* out = (float*)d_out;
  __bf16* wsb = (__bf16*)d_ws;

  prep<<<(PREP_N + 255) / 256, 256, 0, stream>>>(Wp, bp, Wih, Whh, bih, bhead, wsb, out);
  gru_v7<<<1024, 256, 0, stream>>>(x, h0, wsb, bhh, Whead, out);
}

// Round 7
// 251.932 us; speedup vs baseline: 1.1277x; 1.1277x over previous
//
#include <hip/hip_runtime.h>

#define B_N 131072
#define IN_N 40
#define H_N 256

typedef __bf16 bf16x8 __attribute__((ext_vector_type(8)));
typedef float f32x4 __attribute__((ext_vector_type(4)));

#define MFMA(a, b, c) __builtin_amdgcn_mfma_f32_16x16x32_bf16(a, b, c, 0, 0, 0)

// ws bf16 layout (transposed weights: a wave's B-frag load is 1KB contiguous):
//   WT_GH [3][8][256][32] : (gate, ks, col, e) <- Whh[(g*256+col)*256 + ks*32 + e]
//   WT_GI [3][2][256][32] : k=ks2*32+e, fused W_ih@W_proj, zero for k>=40
//   bfused f32[768] = b_ih + W_ih@b_proj
#define WSGH 0
#define WSGI 196608
#define WSBI 245760
#define PREP_N (245760 + 768 + B_N)

__global__ void prep(const float* __restrict__ Wp, const float* __restrict__ bp,
                     const float* __restrict__ Wih, const float* __restrict__ Whh,
                     const float* __restrict__ bih, const float* __restrict__ bhead,
                     __bf16* __restrict__ wsb, float* __restrict__ out) {
  int i = blockIdx.x * 256 + threadIdx.x;
  if (i < WSGI) {
    int e = i & 31, col = (i >> 5) & 255, ks = (i >> 13) & 7, g = i >> 16;
    wsb[i] = (__bf16)Whh[(g * 256 + col) * 256 + ks * 32 + e];
  } else if (i < WSBI) {
    int j = i - WSGI;
    int e = j & 31, col = (j >> 5) & 255, ks2 = (j >> 13) & 1, g = j >> 14;
    int k = ks2 * 32 + e;
    float v = 0.f;
    if (k < IN_N) {
      for (int p = 0; p < 128; ++p) v += Wih[(g * 256 + col) * 128 + p] * Wp[p * IN_N + k];
    }
    wsb[i] = (__bf16)v;
  } else if (i < WSBI + 768) {
    int g = i - WSBI;
    float v = bih[g];
    for (int p = 0; p < 128; ++p) v += Wih[g * 128 + p] * bp[p];
    ((float*)(wsb + WSBI))[g] = v;
  } else if (i < PREP_N) {
    out[i - (WSBI + 768)] = bhead[0];  // pred init = bias; blocks atomicAdd partials
  }
}

// 256 thr = 4 waves; block = 64 rows x 64 H-cols (col quarter). Non-persistent:
// one tile per block, 2 phases (stage -> compute). 3 blocks/CU; latency hidden
// by co-resident + successor blocks. Weights read coalesced from L2 per use.
__global__ __launch_bounds__(256, 3) void gru_v8(
    const float* __restrict__ x, const float* __restrict__ h0,
    const __bf16* __restrict__ wsb, const float* __restrict__ bhh,
    const float* __restrict__ Whead, float* __restrict__ out) {
  __shared__ __align__(16) __bf16 hs[64][264];  // 33792B; 528B stride -> 2-way (free)
  __shared__ __align__(16) __bf16 xs[64][72];   // 9216B; K padded 40->64

  const int tid = threadIdx.x;
  const int lane = tid & 63;
  const int w = tid >> 6;
  const int l15 = lane & 15;
  const int l4 = lane >> 4;
  const int koff = l4 * 8;

  // XCD-chunked swizzle: 4 col-quarters of a row-tile + consecutive row-tiles
  // land on the same XCD -> h/x L2 reuse.
  const int lin = (blockIdx.x & 7) * 1024 + (blockIdx.x >> 3);
  const int ch = lin & 3;
  const int b0 = (lin >> 2) * 64;
  const int col = ch * 64 + w * 16 + l15;

  // ---- phase 0: zero xs pad, stage x and h as bf16 (coalesced 32B chunks) ----
  for (int j = tid; j < 64 * 24; j += 256) xs[j / 24][40 + j % 24] = (__bf16)0.f;
#pragma unroll
  for (int j = 0; j < 2; ++j) {
    const int cid = tid + j * 256;
    if (cid < 320) {
      const int r = cid / 5, cc = cid % 5;
      const float* s = x + (size_t)(b0 + r) * IN_N + cc * 8;
      const float4 a = *reinterpret_cast<const float4*>(s);
      const float4 b = *reinterpret_cast<const float4*>(s + 4);
      bf16x8 u;
      u[0] = (__bf16)a.x; u[1] = (__bf16)a.y; u[2] = (__bf16)a.z; u[3] = (__bf16)a.w;
      u[4] = (__bf16)b.x; u[5] = (__bf16)b.y; u[6] = (__bf16)b.z; u[7] = (__bf16)b.w;
      *reinterpret_cast<bf16x8*>(&xs[r][cc * 8]) = u;
    }
  }
#pragma unroll
  for (int j = 0; j < 8; ++j) {
    const int cid = tid + j * 256;
    const int r = cid >> 5, cc = cid & 31;
    const float* s = h0 + (size_t)(b0 + r) * H_N + cc * 8;
    const float4 a = *reinterpret_cast<const float4*>(s);
    const float4 b = *reinterpret_cast<const float4*>(s + 4);
    bf16x8 u;
    u[0] = (__bf16)a.x; u[1] = (__bf16)a.y; u[2] = (__bf16)a.z; u[3] = (__bf16)a.w;
    u[4] = (__bf16)b.x; u[5] = (__bf16)b.y; u[6] = (__bf16)b.z; u[7] = (__bf16)b.w;
    *reinterpret_cast<bf16x8*>(&hs[r][cc * 8]) = u;
  }
  __syncthreads();

  // ---- phase 1: MFMA ----
  const __bf16* lgh = wsb + WSGH + (size_t)col * 32 + koff;
  const __bf16* lgi = wsb + WSGI + (size_t)col * 32 + koff;
  const float* bfused = (const float*)(wsb + WSBI);
  const float bR = bfused[col] + bhh[col];
  const float bZ = bfused[256 + col] + bhh[256 + col];
  const float bI = bfused[512 + col];
  const float bH = bhh[512 + col];
  const float whead = Whead[col];

  f32x4 aR[4], aZ[4], aI[4], aH[4];
#pragma unroll
  for (int mi = 0; mi < 4; ++mi) {
    aR[mi] = (f32x4){bR, bR, bR, bR};
    aZ[mi] = (f32x4){bZ, bZ, bZ, bZ};
    aI[mi] = (f32x4){bI, bI, bI, bI};
    aH[mi] = (f32x4){bH, bH, bH, bH};
  }

  // gi: K=64 (padded), fused input weights
#pragma unroll
  for (int ks = 0; ks < 2; ++ks) {
    const bf16x8 wR = *reinterpret_cast<const bf16x8*>(lgi + (0 * 2 + ks) * 8192);
    const bf16x8 wZ = *reinterpret_cast<const bf16x8*>(lgi + (1 * 2 + ks) * 8192);
    const bf16x8 wN = *reinterpret_cast<const bf16x8*>(lgi + (2 * 2 + ks) * 8192);
#pragma unroll
    for (int mi = 0; mi < 4; ++mi) {
      const bf16x8 a = *reinterpret_cast<const bf16x8*>(&xs[mi * 16 + l15][ks * 32 + koff]);
      aR[mi] = MFMA(a, wR, aR[mi]);
      aZ[mi] = MFMA(a, wZ, aZ[mi]);
      aI[mi] = MFMA(a, wN, aI[mi]);
    }
  }
  // gh: K=256
#pragma unroll
  for (int ks = 0; ks < 8; ++ks) {
    const bf16x8 wR = *reinterpret_cast<const bf16x8*>(lgh + (0 * 8 + ks) * 8192);
    const bf16x8 wZ = *reinterpret_cast<const bf16x8*>(lgh + (1 * 8 + ks) * 8192);
    const bf16x8 wN = *reinterpret_cast<const bf16x8*>(lgh + (2 * 8 + ks) * 8192);
#pragma unroll
    for (int mi = 0; mi < 4; ++mi) {
      const bf16x8 a = *reinterpret_cast<const bf16x8*>(&hs[mi * 16 + l15][ks * 32 + koff]);
      aR[mi] = MFMA(a, wR, aR[mi]);
      aZ[mi] = MFMA(a, wZ, aZ[mi]);
      aH[mi] = MFMA(a, wN, aH[mi]);
    }
  }

  // ---- epilogue: gates (f32), h_new store, pred partial ----
  float ps[4][4];
#pragma unroll
  for (int mi = 0; mi < 4; ++mi) {
#pragma unroll
    for (int r = 0; r < 4; ++r) {
      const int row = mi * 16 + l4 * 4 + r;
      const float rg = 1.f / (1.f + __expf(-aR[mi][r]));
      const float zg = 1.f / (1.f + __expf(-aZ[mi][r]));
      const float e2 = __expf(2.f * (aI[mi][r] + rg * aH[mi][r]));
      const float ng = (e2 - 1.f) / (e2 + 1.f);
      const float hv = (float)hs[row][col];
      const float hn = (1.f - zg) * ng + zg * hv;
      out[(size_t)B_N + (size_t)(b0 + row) * H_N + col] = hn;
      ps[mi][r] = hn * whead;
    }
  }
#pragma unroll
  for (int mi = 0; mi < 4; ++mi)
#pragma unroll
    for (int r = 0; r < 4; ++r) {
      float s = ps[mi][r];
      s += __shfl_xor(s, 1);
      s += __shfl_xor(s, 2);
      s += __shfl_xor(s, 4);
      s += __shfl_xor(s, 8);
      if (l15 == 0) atomicAdd(&out[b0 + mi * 16 + l4 * 4 + r], s);
    }
}

extern "C" void kernel_launch(void* const* d_in, const int* in_sizes, int n_in,
                              void* d_out, int out_size, void* d_ws, size_t ws_size,
                              hipStream_t stream) {
  const float* x     = (const float*)d_in[0];
  const float* h0    = (const float*)d_in[1];
  const float* Wp    = (const float*)d_in[2];
  const float* bp    = (const float*)d_in[3];
  const float* Wih   = (const float*)d_in[4];
  const float* Whh   = (const float*)d_in[5];
  const float* bih   = (const float*)d_in[6];
  const float* bhh   = (const float*)d_in[7];
  const float* Whead = (const float*)d_in[8];
  const float* bhead = (const float*)d_in[9];
  float* out = (float*)d_out;
  __bf16* wsb = (__bf16*)d_ws;

  prep<<<(PREP_N + 255) / 256, 256, 0, stream>>>(Wp, bp, Wih, Whh, bih, bhead, wsb, out);
  gru_v8<<<8192, 256, 0, stream>>>(x, h0, wsb, bhh, Whead, out);
}